// Round 8
// baseline (224.504 us; speedup 1.0000x reference)
//
#include <hip/hip_runtime.h>
#include <stdint.h>
#include <stddef.h>

#define BB 4
#define CC 128
#define HWN 4096
#define LOG2E 1.4426950408889634f

typedef __bf16 bf16x2 __attribute__((ext_vector_type(2)));
typedef __bf16 bf16x8 __attribute__((ext_vector_type(8)));
typedef float f32x4 __attribute__((ext_vector_type(4)));

// fragment permutation within 32-element groups: x = 16h+4g+j -> 8g+4h+j
__device__ __forceinline__ int perm32(int x) {
  return ((x & 12) << 1) | ((x & 16) >> 2) | (x & 3);
}

// ---------------- W2 = out_w @ g1w, b2 = out_w @ g1b (f32, tiny) ----------------
__global__ __launch_bounds__(128) void w2prep_kernel(
    const float* __restrict__ outw, const float* __restrict__ g1w,
    const float* __restrict__ g1b, float* __restrict__ W2, float* __restrict__ b2) {
  int o = blockIdx.x;
  int c = threadIdx.x;
  float acc = 0.f;
#pragma unroll 8
  for (int k = 0; k < CC; ++k)
    acc = fmaf(outw[o * CC + k], g1w[k * CC + c], acc);
  W2[o * CC + c] = acc;
  if (c == 0) {
    float s = 0.f;
#pragma unroll 8
    for (int k = 0; k < CC; ++k) s = fmaf(outw[o * CC + k], g1b[k], s);
    b2[o] = s;
  }
}

// ---------------- per-(b,c) mean/rstd over HW (unbiased var, +eps) -------------
__global__ __launch_bounds__(256) void moments_kernel(
    const float* __restrict__ content, const float* __restrict__ guidance,
    float2* __restrict__ mom) {
  int row = blockIdx.x;  // b*C + c
  const float* x = (blockIdx.y ? guidance : content) + (size_t)row * HWN;
  int tid = threadIdx.x;
  float s1 = 0.f, s2 = 0.f;
#pragma unroll
  for (int i = 0; i < 16; ++i) {
    float v = x[tid + i * 256];
    s1 += v; s2 += v * v;
  }
#pragma unroll
  for (int off = 32; off > 0; off >>= 1) {
    s1 += __shfl_down(s1, off);
    s2 += __shfl_down(s2, off);
  }
  __shared__ float r1[4], r2[4];
  int wid = tid >> 6;
  if ((tid & 63) == 0) { r1[wid] = s1; r2[wid] = s2; }
  __syncthreads();
  if (tid == 0) {
    float t1 = r1[0] + r1[1] + r1[2] + r1[3];
    float t2 = r2[0] + r2[1] + r2[2] + r2[3];
    float mean = t1 * (1.f / HWN);
    float var = (t2 - (float)HWN * mean * mean) * (1.f / (HWN - 1));
    mom[blockIdx.y * (BB * CC) + row] = make_float2(mean, rsqrtf(var + 1e-5f));
  }
}

// ---------------- 1x1 conv: 4 modes, one launch, 2 p per thread -----------------
// zc = blockIdx.z; mode = zc>>1; ohalf = zc&1 (64 outputs per block).
// mode 0: KT  = bf16(g1w@mvn(content)+g1b), transposed [p][permc]
// mode 1: QT  = bf16((fw@mvn(guidance)+fb)*LOG2E), transposed [p][permc]
// mode 2: V   = bf16(hw@guidance+hb), [c][perm p]
// mode 3: T   = W2@mvn(content)+b2, f32 [c][p]  (G1 never materialized)
__global__ __launch_bounds__(256, 4) void conv_kernel(
    const float* __restrict__ content, const float* __restrict__ guidance,
    const float* __restrict__ g1w, const float* __restrict__ g1b,
    const float* __restrict__ fw, const float* __restrict__ fb,
    const float* __restrict__ hwt, const float* __restrict__ hb,
    const float* __restrict__ W2, const float* __restrict__ b2,
    const float2* __restrict__ mom,
    float* __restrict__ Tf,
    __bf16* __restrict__ QTb, __bf16* __restrict__ KTb, __bf16* __restrict__ Vb) {
  int zc = blockIdx.z;
  int mode = zc >> 1;
  int ohalf = zc & 1;
  int b = blockIdx.y;
  int lane = threadIdx.x & 63;
  int wid = threadIdx.x >> 6;
  int swid = __builtin_amdgcn_readfirstlane(wid);
  int p0 = blockIdx.x * 128 + lane * 2;
  const float* x; const float* w; const float* bias; const float2* mm;
  if (mode == 0)      { x = content;  w = g1w; bias = g1b; mm = mom; }
  else if (mode == 1) { x = guidance; w = fw;  bias = fb;  mm = mom + BB * CC; }
  else if (mode == 2) { x = guidance; w = hwt; bias = hb;  mm = nullptr; }
  else                { x = content;  w = W2;  bias = b2;  mm = mom; }
  const float* xb = x + (size_t)b * CC * HWN;
  const float2* mb = mm ? mm + b * CC : nullptr;
  int obase = ohalf * 64 + 2 * wid;
  const float* wbase = w + (size_t)(ohalf * 64 + 2 * swid) * CC;  // scalar base
  float2 acc[16];
#pragma unroll
  for (int k = 0; k < 8; ++k) {
    float b0 = bias[obase + 8 * k], b1 = bias[obase + 8 * k + 1];
    acc[2 * k] = make_float2(b0, b0);
    acc[2 * k + 1] = make_float2(b1, b1);
  }
#pragma unroll 2
  for (int c0 = 0; c0 < CC; c0 += 4) {
    float2 xv[4];
#pragma unroll
    for (int j = 0; j < 4; ++j) {
      float2 raw = *(const float2*)(xb + (size_t)(c0 + j) * HWN + p0);
      if (mb) {
        float2 ms = mb[c0 + j];
        raw.x = (raw.x - ms.x) * ms.y;
        raw.y = (raw.y - ms.x) * ms.y;
      }
      xv[j] = raw;
    }
#pragma unroll
    for (int k = 0; k < 8; ++k) {
      const float4 w0 = *(const float4*)(wbase + (size_t)(8 * k) * CC + c0);
      const float4 w1 = *(const float4*)(wbase + (size_t)(8 * k + 1) * CC + c0);
      acc[2 * k].x     = fmaf(w0.x, xv[0].x, fmaf(w0.y, xv[1].x, fmaf(w0.z, xv[2].x, fmaf(w0.w, xv[3].x, acc[2 * k].x))));
      acc[2 * k].y     = fmaf(w0.x, xv[0].y, fmaf(w0.y, xv[1].y, fmaf(w0.z, xv[2].y, fmaf(w0.w, xv[3].y, acc[2 * k].y))));
      acc[2 * k + 1].x = fmaf(w1.x, xv[0].x, fmaf(w1.y, xv[1].x, fmaf(w1.z, xv[2].x, fmaf(w1.w, xv[3].x, acc[2 * k + 1].x))));
      acc[2 * k + 1].y = fmaf(w1.x, xv[0].y, fmaf(w1.y, xv[1].y, fmaf(w1.z, xv[2].y, fmaf(w1.w, xv[3].y, acc[2 * k + 1].y))));
    }
  }
  if (mode <= 1) {
    __bf16* T = (mode == 0) ? KTb : QTb;
    float scale = (mode == 1) ? LOG2E : 1.f;
    char* row0 = (char*)(T + ((size_t)b * HWN + p0) * CC);
    char* row1 = row0 + CC * 2;
#pragma unroll
    for (int k = 0; k < 8; ++k) {
      int o0 = obase + 8 * k;
      int pp = (o0 & ~31) | perm32(o0 & 31);  // o0 even -> pp, pp+1 adjacent
      bf16x2 pr0 = {(__bf16)(acc[2 * k].x * scale), (__bf16)(acc[2 * k + 1].x * scale)};
      bf16x2 pr1 = {(__bf16)(acc[2 * k].y * scale), (__bf16)(acc[2 * k + 1].y * scale)};
      *(bf16x2*)(row0 + pp * 2) = pr0;
      *(bf16x2*)(row1 + pp * 2) = pr1;
    }
  } else if (mode == 2) {
    int pstore = (p0 & ~31) | perm32(p0 & 31);  // p0 even -> +1 adjacent
#pragma unroll
    for (int k = 0; k < 8; ++k) {
      int o0 = obase + 8 * k;
      bf16x2 v0 = {(__bf16)acc[2 * k].x, (__bf16)acc[2 * k].y};
      bf16x2 v1 = {(__bf16)acc[2 * k + 1].x, (__bf16)acc[2 * k + 1].y};
      *(bf16x2*)(Vb + ((size_t)b * CC + o0) * HWN + pstore) = v0;
      *(bf16x2*)(Vb + ((size_t)b * CC + o0 + 1) * HWN + pstore) = v1;
    }
  } else {
#pragma unroll
    for (int k = 0; k < 8; ++k) {
      int o0 = obase + 8 * k;
      *(float2*)(Tf + ((size_t)b * CC + o0) * HWN + p0) = acc[2 * k];
      *(float2*)(Tf + ((size_t)b * CC + o0 + 1) * HWN + p0) = acc[2 * k + 1];
    }
  }
}

// ---------------- flash attention: G2_pre[c,n] = sum_m V[c,m]*softmax_m(S[n,m]) --
// Barrier-free, LDS-free main loop: each wave loads its K/V MFMA fragments
// DIRECTLY from global (L2-resident; perm32 layouts make fragments 16B-contig).
// K double-buffered (1-iter lead), V single-buffered (issued at iter top,
// consumed after QK^T+softmax). 8 waves = 4 m-groups x 2 n-halves; merge at end.
__global__ __launch_bounds__(512, 2) void attn_kernel(
    const __bf16* __restrict__ QTb, const __bf16* __restrict__ KTb,
    const __bf16* __restrict__ Vb, float* __restrict__ G2p) {
  __shared__ __align__(16) float xch[384 * 69];  // merge exchange only
  int fid = blockIdx.x;
  int swz = (fid & 7) * 32 + (fid >> 3);  // XCD swizzle
  int b = swz >> 6;
  int ntile = swz & 63;
  int tid = threadIdx.x;
  int lane = tid & 63;
  int wid = tid >> 6;   // 0..7
  int grp = wid >> 1;   // m-group: wave handles tiles 4*i+grp, i=0..31
  int w2 = wid & 1;     // n-half
  int l15 = lane & 15;
  int g = lane >> 4;

  bf16x8 qf[2][4];
#pragma unroll
  for (int st = 0; st < 2; ++st) {
    const __bf16* qrow = QTb + ((size_t)b * HWN + ntile * 64 + w2 * 32 + st * 16 + l15) * CC;
#pragma unroll
    for (int ch = 0; ch < 4; ++ch)
      qf[st][ch] = *(const bf16x8*)(qrow + ch * 32 + g * 8);
  }

  f32x4 Of[2][8];
#pragma unroll
  for (int st = 0; st < 2; ++st)
#pragma unroll
    for (int cs = 0; cs < 8; ++cs) Of[st][cs] = (f32x4){0.f, 0.f, 0.f, 0.f};
  float mrun[2] = {-1e30f, -1e30f}, lrun[2] = {0.f, 0.f};

  // lane-constant bases; per-tile adds are wave-uniform
  const char* ktB = (const char*)(KTb + (size_t)b * HWN * CC);  // [m][permc] 256B rows
  const char* vB  = (const char*)(Vb + (size_t)b * CC * HWN);   // [c][perm m] 8192B rows
  const char* kbase = ktB + (size_t)l15 * 256 + g * 16;
  const char* vbase = vB + (size_t)l15 * 8192 + g * 16;

  bf16x8 kfA[2][4], kfB[2][4], vf[8];

  auto loadK = [&](bf16x8 (&kf)[2][4], int i) {
    size_t off = (size_t)(4 * i + grp) * 8192;  // m0*256, m0 = (4i+grp)*32
#pragma unroll
    for (int ms = 0; ms < 2; ++ms)
#pragma unroll
      for (int ch = 0; ch < 4; ++ch)
        kf[ms][ch] = *(const bf16x8*)(kbase + off + ms * 4096 + ch * 64);
  };
  auto loadV = [&](int i) {
    size_t off = (size_t)(4 * i + grp) * 64;    // m0*2 bytes
#pragma unroll
    for (int cs = 0; cs < 8; ++cs)
      vf[cs] = *(const bf16x8*)(vbase + off + (size_t)cs * 131072);
  };

  auto step = [&](bf16x8 (&kfU)[2][4], bf16x8 (&kfN)[2][4], int i) {
    loadV(i);  // V(i): consumed after QK^T + softmax (~400cyc lead)
    f32x4 sacc[2][2];
#pragma unroll
    for (int st = 0; st < 2; ++st)
#pragma unroll
      for (int ms = 0; ms < 2; ++ms) sacc[st][ms] = (f32x4){0.f, 0.f, 0.f, 0.f};
    __builtin_amdgcn_s_setprio(1);
#pragma unroll
    for (int ch = 0; ch < 4; ++ch)
#pragma unroll
      for (int st = 0; st < 2; ++st)
#pragma unroll
        for (int ms = 0; ms < 2; ++ms)
          sacc[st][ms] = __builtin_amdgcn_mfma_f32_16x16x32_bf16(kfU[ms][ch], qf[st][ch], sacc[st][ms], 0, 0, 0);
    __builtin_amdgcn_s_setprio(0);
    loadK(kfN, (i + 1 < 32) ? i + 1 : 31);  // K(i+1): full-iteration lead
    bf16x8 pf[2];
#pragma unroll
    for (int st = 0; st < 2; ++st) {
      float tm = -1e30f;
#pragma unroll
      for (int ms = 0; ms < 2; ++ms)
#pragma unroll
        for (int r = 0; r < 4; ++r) tm = fmaxf(tm, sacc[st][ms][r]);
      tm = fmaxf(tm, __shfl_xor(tm, 16));
      tm = fmaxf(tm, __shfl_xor(tm, 32));
      if (!__all(tm <= mrun[st] + 8.f)) {  // defer-max (base-2: P <= 2^8)
        float mnew = fmaxf(mrun[st], tm);
        float alpha = exp2f(mrun[st] - mnew);
        lrun[st] *= alpha;
#pragma unroll
        for (int cs = 0; cs < 8; ++cs) Of[st][cs] *= alpha;
        mrun[st] = mnew;
      }
      float ps = 0.f;
#pragma unroll
      for (int ms = 0; ms < 2; ++ms)
#pragma unroll
        for (int r = 0; r < 4; ++r) {
          float e = exp2f(sacc[st][ms][r] - mrun[st]);
          sacc[st][ms][r] = e;
          ps += e;
        }
      ps += __shfl_xor(ps, 16);
      ps += __shfl_xor(ps, 32);
      lrun[st] += ps;
#pragma unroll
      for (int j = 0; j < 8; ++j)
        pf[st][j] = (__bf16)sacc[st][j >> 2][j & 3];
    }
    __builtin_amdgcn_s_setprio(1);
#pragma unroll
    for (int cs = 0; cs < 8; ++cs)
#pragma unroll
      for (int st = 0; st < 2; ++st)
        Of[st][cs] = __builtin_amdgcn_mfma_f32_16x16x32_bf16(vf[cs], pf[st], Of[st][cs], 0, 0, 0);
    __builtin_amdgcn_s_setprio(0);
  };

  loadK(kfA, 0);
#pragma unroll 1
  for (int i = 0; i < 32; i += 2) {
    step(kfA, kfB, i);
    step(kfB, kfA, i + 1);
  }

  // 4-way merge: groups 1..3 write partials, group 0 combines.
  __syncthreads();
  if (grp) {
    float* rec = xch + (size_t)((grp - 1) * 128 + w2 * 64 + lane) * 69;
#pragma unroll
    for (int st = 0; st < 2; ++st) {
#pragma unroll
      for (int cs = 0; cs < 8; ++cs)
#pragma unroll
        for (int q = 0; q < 4; ++q) rec[st * 34 + cs * 4 + q] = Of[st][cs][q];
      rec[st * 34 + 32] = mrun[st];
      rec[st * 34 + 33] = lrun[st];
    }
  }
  __syncthreads();
  if (grp == 0) {
    float* outp = G2p + (size_t)b * CC * HWN;
#pragma unroll
    for (int st = 0; st < 2; ++st) {
      const float* r1 = xch + (size_t)(0 * 128 + w2 * 64 + lane) * 69 + st * 34;
      const float* r2 = xch + (size_t)(1 * 128 + w2 * 64 + lane) * 69 + st * 34;
      const float* r3 = xch + (size_t)(2 * 128 + w2 * 64 + lane) * 69 + st * 34;
      float m1 = r1[32], m2 = r2[32], m3 = r3[32];
      float mm = fmaxf(fmaxf(mrun[st], m1), fmaxf(m2, m3));
      float a0 = exp2f(mrun[st] - mm), a1 = exp2f(m1 - mm);
      float a2 = exp2f(m2 - mm), a3 = exp2f(m3 - mm);
      float inv = 1.f / (lrun[st] * a0 + r1[33] * a1 + r2[33] * a2 + r3[33] * a3);
      int n_l = ntile * 64 + w2 * 32 + st * 16 + l15;
#pragma unroll
      for (int cs = 0; cs < 8; ++cs)
#pragma unroll
        for (int q = 0; q < 4; ++q) {
          float v = Of[st][cs][q] * a0 + r1[cs * 4 + q] * a1 + r2[cs * 4 + q] * a2 + r3[cs * 4 + q] * a3;
          outp[(size_t)(cs * 16 + 4 * g + q) * HWN + n_l] = v * inv;
        }
    }
  }
}

// ---------------- per-(b,c) row softmax stats of G2_pre over n ------------------
__global__ __launch_bounds__(256) void smstats_kernel(
    const float* __restrict__ G2p, float2* __restrict__ smst) {
  int row = blockIdx.x;
  const float* x = G2p + (size_t)row * HWN;
  int tid = threadIdx.x;
  float v[16];
  float mx = -1e30f;
#pragma unroll
  for (int i = 0; i < 16; ++i) { v[i] = x[tid + i * 256]; mx = fmaxf(mx, v[i]); }
#pragma unroll
  for (int off = 32; off > 0; off >>= 1) mx = fmaxf(mx, __shfl_xor(mx, off));
  __shared__ float rm[4], rs[4];
  int wid = tid >> 6;
  if ((tid & 63) == 0) rm[wid] = mx;
  __syncthreads();
  float bmax = fmaxf(fmaxf(rm[0], rm[1]), fmaxf(rm[2], rm[3]));
  float s = 0.f;
#pragma unroll
  for (int i = 0; i < 16; ++i) s += __expf(v[i] - bmax);
#pragma unroll
  for (int off = 32; off > 0; off >>= 1) s += __shfl_xor(s, off);
  if ((tid & 63) == 0) rs[wid] = s;
  __syncthreads();
  if (tid == 0) {
    float tot = rs[0] + rs[1] + rs[2] + rs[3];
    smst[row] = make_float2(bmax, 1.f / tot);
  }
}

// ---------------- gamma/beta = channel-weighted sums of softmaxed G2 ------------
__global__ __launch_bounds__(256) void gammabeta_kernel(
    const float* __restrict__ G2p, const float2* __restrict__ smst,
    const float* __restrict__ gw, const float* __restrict__ bw,
    float* __restrict__ gamma, float* __restrict__ beta) {
  int b = blockIdx.y;
  int lane = threadIdx.x & 63;
  int cg = threadIdx.x >> 6;
  int m = blockIdx.x * 64 + lane;
  const float* base = G2p + (size_t)b * CC * HWN + m;
  float ag = 0.f, ab = 0.f;
#pragma unroll 8
  for (int ci = 0; ci < 32; ++ci) {
    int c = cg * 32 + ci;
    float2 st = smst[b * CC + c];
    float val = __expf(base[(size_t)c * HWN] - st.x) * st.y;
    ag = fmaf(gw[c], val, ag);
    ab = fmaf(bw[c], val, ab);
  }
  __shared__ float sg[4][64], sb[4][64];
  sg[cg][lane] = ag;
  sb[cg][lane] = ab;
  __syncthreads();
  if (threadIdx.x < 64) {
    int t = threadIdx.x;
    gamma[b * HWN + blockIdx.x * 64 + t] = sg[0][t] + sg[1][t] + sg[2][t] + sg[3][t];
    beta[b * HWN + blockIdx.x * 64 + t]  = sb[0][t] + sb[1][t] + sb[2][t] + sb[3][t];
  }
}

// ---- out[b,o] = T[b,o]@Gam[b] + rowsum(out_w[o,:])*Beta[b] + out_b[o] ----------
__global__ __launch_bounds__(256) void final_kernel(
    const float* __restrict__ Tf, const float* __restrict__ gamma,
    const float* __restrict__ beta, const float* __restrict__ outw,
    const float* __restrict__ outb, float* __restrict__ out) {
  int o = blockIdx.x, b = blockIdx.y;
  int j = threadIdx.x & 63;
  int wid = __builtin_amdgcn_readfirstlane(threadIdx.x >> 6);
  const float* gb_ = gamma + (size_t)b * HWN;
  float gr[64];
#pragma unroll
  for (int k = 0; k < 64; ++k) gr[k] = gb_[k * 64 + j];
  float wb = 0.f;
#pragma unroll 16
  for (int c = 0; c < CC; ++c) wb += outw[o * CC + c];
  float ob = outb[o];
  const float* trow0 = Tf + ((size_t)b * CC + o) * HWN;
  const float* bbase = beta + (size_t)b * HWN;
  float* obase = out + ((size_t)b * CC + o) * HWN;
#pragma unroll 4
  for (int r = 0; r < 16; ++r) {
    int i = r * 4 + wid;
    const float* tr = trow0 + i * 64;
    float a0 = 0.f, a1 = 0.f, a2 = 0.f, a3 = 0.f;
#pragma unroll
    for (int k = 0; k < 64; k += 4) {
      a0 = fmaf(tr[k],     gr[k],     a0);
      a1 = fmaf(tr[k + 1], gr[k + 1], a1);
      a2 = fmaf(tr[k + 2], gr[k + 2], a2);
      a3 = fmaf(tr[k + 3], gr[k + 3], a3);
    }
    obase[i * 64 + j] = (a0 + a1) + (a2 + a3) + wb * bbase[i * 64 + j] + ob;
  }
}

extern "C" void kernel_launch(void* const* d_in, const int* in_sizes, int n_in,
                              void* d_out, int out_size, void* d_ws, size_t ws_size,
                              hipStream_t stream) {
  (void)in_sizes; (void)n_in; (void)out_size; (void)ws_size;
  const float* content  = (const float*)d_in[0];
  const float* guidance = (const float*)d_in[1];
  const float* g1w = (const float*)d_in[2];
  const float* g1b = (const float*)d_in[3];
  const float* fw  = (const float*)d_in[4];
  const float* fb  = (const float*)d_in[5];
  const float* hwt = (const float*)d_in[6];
  const float* hb  = (const float*)d_in[7];
  const float* gw  = (const float*)d_in[8];
  const float* bw  = (const float*)d_in[9];
  const float* outw = (const float*)d_in[10];
  const float* outb = (const float*)d_in[11];

  char* ws = (char*)d_ws;
  const size_t MB_ = 1u << 20;
  float*  Tf  = (float*)(ws + 0);            // 8 MB
  float*  G2p = (float*)(ws + 8 * MB_);      // 8 MB
  __bf16* QTb = (__bf16*)(ws + 16 * MB_);    // 4 MB
  __bf16* KTb = (__bf16*)(ws + 20 * MB_);    // 4 MB
  __bf16* Vb  = (__bf16*)(ws + 24 * MB_);    // 4 MB
  float2* mom  = (float2*)(ws + 28 * MB_);                  // 8 KB
  float2* smst = (float2*)(ws + 28 * MB_ + 8192);           // 4 KB
  float*  gamma = (float*)(ws + 28 * MB_ + 16384);          // 64 KB
  float*  beta  = (float*)(ws + 28 * MB_ + 16384 + 65536);  // 64 KB
  float*  W2 = (float*)(ws + 28 * MB_ + 16384 + 2 * 65536); // 64 KB
  float*  b2 = (float*)(ws + 28 * MB_ + 16384 + 3 * 65536); // 512 B

  w2prep_kernel<<<dim3(CC), 128, 0, stream>>>(outw, g1w, g1b, W2, b2);
  moments_kernel<<<dim3(BB * CC, 2), 256, 0, stream>>>(content, guidance, mom);
  conv_kernel<<<dim3(HWN / 128, BB, 8), 256, 0, stream>>>(
      content, guidance, g1w, g1b, fw, fb, hwt, hb, W2, b2, mom,
      Tf, QTb, KTb, Vb);
  attn_kernel<<<dim3(256), 512, 0, stream>>>(QTb, KTb, Vb, G2p);
  smstats_kernel<<<dim3(BB * CC), 256, 0, stream>>>(G2p, smst);
  gammabeta_kernel<<<dim3(HWN / 64, BB), 256, 0, stream>>>(G2p, smst, gw, bw, gamma, beta);
  final_kernel<<<dim3(CC, BB), 256, 0, stream>>>(Tf, gamma, beta, outw, outb, (float*)d_out);
}

// Round 9
// 224.441 us; speedup vs baseline: 1.0003x; 1.0003x over previous
//
#include <hip/hip_runtime.h>
#include <stdint.h>
#include <stddef.h>

#define BB 4
#define CC 128
#define HWN 4096
#define LOG2E 1.4426950408889634f

typedef __bf16 bf16x2 __attribute__((ext_vector_type(2)));
typedef __bf16 bf16x8 __attribute__((ext_vector_type(8)));
typedef float f32x4 __attribute__((ext_vector_type(4)));

// fragment permutation within 32-element groups: x = 16h+4g+j -> 8g+4h+j
__device__ __forceinline__ int perm32(int x) {
  return ((x & 12) << 1) | ((x & 16) >> 2) | (x & 3);
}

// ---------------- W2 = out_w @ g1w, b2 = out_w @ g1b (f32, tiny) ----------------
__global__ __launch_bounds__(128) void w2prep_kernel(
    const float* __restrict__ outw, const float* __restrict__ g1w,
    const float* __restrict__ g1b, float* __restrict__ W2, float* __restrict__ b2) {
  int o = blockIdx.x;
  int c = threadIdx.x;
  float acc = 0.f;
#pragma unroll 8
  for (int k = 0; k < CC; ++k)
    acc = fmaf(outw[o * CC + k], g1w[k * CC + c], acc);
  W2[o * CC + c] = acc;
  if (c == 0) {
    float s = 0.f;
#pragma unroll 8
    for (int k = 0; k < CC; ++k) s = fmaf(outw[o * CC + k], g1b[k], s);
    b2[o] = s;
  }
}

// ---------------- per-(b,c) mean/rstd over HW (unbiased var, +eps) -------------
__global__ __launch_bounds__(256) void moments_kernel(
    const float* __restrict__ content, const float* __restrict__ guidance,
    float2* __restrict__ mom) {
  int row = blockIdx.x;  // b*C + c
  const float* x = (blockIdx.y ? guidance : content) + (size_t)row * HWN;
  int tid = threadIdx.x;
  float s1 = 0.f, s2 = 0.f;
#pragma unroll
  for (int i = 0; i < 16; ++i) {
    float v = x[tid + i * 256];
    s1 += v; s2 += v * v;
  }
#pragma unroll
  for (int off = 32; off > 0; off >>= 1) {
    s1 += __shfl_down(s1, off);
    s2 += __shfl_down(s2, off);
  }
  __shared__ float r1[4], r2[4];
  int wid = tid >> 6;
  if ((tid & 63) == 0) { r1[wid] = s1; r2[wid] = s2; }
  __syncthreads();
  if (tid == 0) {
    float t1 = r1[0] + r1[1] + r1[2] + r1[3];
    float t2 = r2[0] + r2[1] + r2[2] + r2[3];
    float mean = t1 * (1.f / HWN);
    float var = (t2 - (float)HWN * mean * mean) * (1.f / (HWN - 1));
    mom[blockIdx.y * (BB * CC) + row] = make_float2(mean, rsqrtf(var + 1e-5f));
  }
}

// ---------------- 1x1 conv: 4 modes, one launch, 2 p per thread -----------------
// zc = blockIdx.z; mode = zc>>1; ohalf = zc&1 (64 outputs per block).
// mode 0: KT  = bf16(g1w@mvn(content)+g1b), transposed [p][permc]
// mode 1: QT  = bf16((fw@mvn(guidance)+fb)*LOG2E), transposed [p][permc]
// mode 2: V   = bf16(hw@guidance+hb), [c][perm p]
// mode 3: T   = W2@mvn(content)+b2, f32 [c][p]  (G1 never materialized)
__global__ __launch_bounds__(256, 4) void conv_kernel(
    const float* __restrict__ content, const float* __restrict__ guidance,
    const float* __restrict__ g1w, const float* __restrict__ g1b,
    const float* __restrict__ fw, const float* __restrict__ fb,
    const float* __restrict__ hwt, const float* __restrict__ hb,
    const float* __restrict__ W2, const float* __restrict__ b2,
    const float2* __restrict__ mom,
    float* __restrict__ Tf,
    __bf16* __restrict__ QTb, __bf16* __restrict__ KTb, __bf16* __restrict__ Vb) {
  int zc = blockIdx.z;
  int mode = zc >> 1;
  int ohalf = zc & 1;
  int b = blockIdx.y;
  int lane = threadIdx.x & 63;
  int wid = threadIdx.x >> 6;
  int swid = __builtin_amdgcn_readfirstlane(wid);
  int p0 = blockIdx.x * 128 + lane * 2;
  const float* x; const float* w; const float* bias; const float2* mm;
  if (mode == 0)      { x = content;  w = g1w; bias = g1b; mm = mom; }
  else if (mode == 1) { x = guidance; w = fw;  bias = fb;  mm = mom + BB * CC; }
  else if (mode == 2) { x = guidance; w = hwt; bias = hb;  mm = nullptr; }
  else                { x = content;  w = W2;  bias = b2;  mm = mom; }
  const float* xb = x + (size_t)b * CC * HWN;
  const float2* mb = mm ? mm + b * CC : nullptr;
  int obase = ohalf * 64 + 2 * wid;
  const float* wbase = w + (size_t)(ohalf * 64 + 2 * swid) * CC;  // scalar base
  float2 acc[16];
#pragma unroll
  for (int k = 0; k < 8; ++k) {
    float b0 = bias[obase + 8 * k], b1 = bias[obase + 8 * k + 1];
    acc[2 * k] = make_float2(b0, b0);
    acc[2 * k + 1] = make_float2(b1, b1);
  }
#pragma unroll 2
  for (int c0 = 0; c0 < CC; c0 += 4) {
    float2 xv[4];
#pragma unroll
    for (int j = 0; j < 4; ++j) {
      float2 raw = *(const float2*)(xb + (size_t)(c0 + j) * HWN + p0);
      if (mb) {
        float2 ms = mb[c0 + j];
        raw.x = (raw.x - ms.x) * ms.y;
        raw.y = (raw.y - ms.x) * ms.y;
      }
      xv[j] = raw;
    }
#pragma unroll
    for (int k = 0; k < 8; ++k) {
      const float4 w0 = *(const float4*)(wbase + (size_t)(8 * k) * CC + c0);
      const float4 w1 = *(const float4*)(wbase + (size_t)(8 * k + 1) * CC + c0);
      acc[2 * k].x     = fmaf(w0.x, xv[0].x, fmaf(w0.y, xv[1].x, fmaf(w0.z, xv[2].x, fmaf(w0.w, xv[3].x, acc[2 * k].x))));
      acc[2 * k].y     = fmaf(w0.x, xv[0].y, fmaf(w0.y, xv[1].y, fmaf(w0.z, xv[2].y, fmaf(w0.w, xv[3].y, acc[2 * k].y))));
      acc[2 * k + 1].x = fmaf(w1.x, xv[0].x, fmaf(w1.y, xv[1].x, fmaf(w1.z, xv[2].x, fmaf(w1.w, xv[3].x, acc[2 * k + 1].x))));
      acc[2 * k + 1].y = fmaf(w1.x, xv[0].y, fmaf(w1.y, xv[1].y, fmaf(w1.z, xv[2].y, fmaf(w1.w, xv[3].y, acc[2 * k + 1].y))));
    }
  }
  if (mode <= 1) {
    __bf16* T = (mode == 0) ? KTb : QTb;
    float scale = (mode == 1) ? LOG2E : 1.f;
    char* row0 = (char*)(T + ((size_t)b * HWN + p0) * CC);
    char* row1 = row0 + CC * 2;
#pragma unroll
    for (int k = 0; k < 8; ++k) {
      int o0 = obase + 8 * k;
      int pp = (o0 & ~31) | perm32(o0 & 31);  // o0 even -> pp, pp+1 adjacent
      bf16x2 pr0 = {(__bf16)(acc[2 * k].x * scale), (__bf16)(acc[2 * k + 1].x * scale)};
      bf16x2 pr1 = {(__bf16)(acc[2 * k].y * scale), (__bf16)(acc[2 * k + 1].y * scale)};
      *(bf16x2*)(row0 + pp * 2) = pr0;
      *(bf16x2*)(row1 + pp * 2) = pr1;
    }
  } else if (mode == 2) {
    int pstore = (p0 & ~31) | perm32(p0 & 31);  // p0 even -> +1 adjacent
#pragma unroll
    for (int k = 0; k < 8; ++k) {
      int o0 = obase + 8 * k;
      bf16x2 v0 = {(__bf16)acc[2 * k].x, (__bf16)acc[2 * k].y};
      bf16x2 v1 = {(__bf16)acc[2 * k + 1].x, (__bf16)acc[2 * k + 1].y};
      *(bf16x2*)(Vb + ((size_t)b * CC + o0) * HWN + pstore) = v0;
      *(bf16x2*)(Vb + ((size_t)b * CC + o0 + 1) * HWN + pstore) = v1;
    }
  } else {
#pragma unroll
    for (int k = 0; k < 8; ++k) {
      int o0 = obase + 8 * k;
      *(float2*)(Tf + ((size_t)b * CC + o0) * HWN + p0) = acc[2 * k];
      *(float2*)(Tf + ((size_t)b * CC + o0 + 1) * HWN + p0) = acc[2 * k + 1];
    }
  }
}

// ---------------- flash attention: G2_pre[c,n] = sum_m V[c,m]*softmax_m(S[n,m]) --
// Barrier-free, LDS-free main loop: each wave loads its K/V MFMA fragments
// DIRECTLY from global (L2-resident; perm32 layouts make fragments 16B-contig).
// K double-buffered (1-iter lead), V single-buffered (issued at iter top,
// consumed after QK^T+softmax). 8 waves = 4 m-groups x 2 n-halves; merge at end.
__global__ __launch_bounds__(512, 2) void attn_kernel(
    const __bf16* __restrict__ QTb, const __bf16* __restrict__ KTb,
    const __bf16* __restrict__ Vb, float* __restrict__ G2p) {
  __shared__ __align__(16) float xch[384 * 69];  // merge exchange only
  int fid = blockIdx.x;
  int swz = (fid & 7) * 32 + (fid >> 3);  // XCD swizzle
  int b = swz >> 6;
  int ntile = swz & 63;
  int tid = threadIdx.x;
  int lane = tid & 63;
  int wid = tid >> 6;   // 0..7
  int grp = wid >> 1;   // m-group: wave handles tiles 4*i+grp, i=0..31
  int w2 = wid & 1;     // n-half
  int l15 = lane & 15;
  int g = lane >> 4;

  bf16x8 qf[2][4];
#pragma unroll
  for (int st = 0; st < 2; ++st) {
    const __bf16* qrow = QTb + ((size_t)b * HWN + ntile * 64 + w2 * 32 + st * 16 + l15) * CC;
#pragma unroll
    for (int ch = 0; ch < 4; ++ch)
      qf[st][ch] = *(const bf16x8*)(qrow + ch * 32 + g * 8);
  }

  f32x4 Of[2][8];
#pragma unroll
  for (int st = 0; st < 2; ++st)
#pragma unroll
    for (int cs = 0; cs < 8; ++cs) Of[st][cs] = (f32x4){0.f, 0.f, 0.f, 0.f};
  float mrun[2] = {-1e30f, -1e30f}, lrun[2] = {0.f, 0.f};

  // lane-constant bases; per-tile adds are wave-uniform
  const char* ktB = (const char*)(KTb + (size_t)b * HWN * CC);  // [m][permc] 256B rows
  const char* vB  = (const char*)(Vb + (size_t)b * CC * HWN);   // [c][perm m] 8192B rows
  const char* kbase = ktB + (size_t)l15 * 256 + g * 16;
  const char* vbase = vB + (size_t)l15 * 8192 + g * 16;

  bf16x8 kfA[2][4], kfB[2][4], vf[8];

  auto loadK = [&](bf16x8 (&kf)[2][4], int i) {
    size_t off = (size_t)(4 * i + grp) * 8192;  // m0*256, m0 = (4i+grp)*32
#pragma unroll
    for (int ms = 0; ms < 2; ++ms)
#pragma unroll
      for (int ch = 0; ch < 4; ++ch)
        kf[ms][ch] = *(const bf16x8*)(kbase + off + ms * 4096 + ch * 64);
  };
  auto loadV = [&](int i) {
    size_t off = (size_t)(4 * i + grp) * 64;    // m0*2 bytes
#pragma unroll
    for (int cs = 0; cs < 8; ++cs)
      vf[cs] = *(const bf16x8*)(vbase + off + (size_t)cs * 131072);
  };

  auto step = [&](bf16x8 (&kfU)[2][4], bf16x8 (&kfN)[2][4], int i) {
    loadV(i);  // V(i): consumed after QK^T + softmax (~400cyc lead)
    f32x4 sacc[2][2];
#pragma unroll
    for (int st = 0; st < 2; ++st)
#pragma unroll
      for (int ms = 0; ms < 2; ++ms) sacc[st][ms] = (f32x4){0.f, 0.f, 0.f, 0.f};
    __builtin_amdgcn_s_setprio(1);
#pragma unroll
    for (int ch = 0; ch < 4; ++ch)
#pragma unroll
      for (int st = 0; st < 2; ++st)
#pragma unroll
        for (int ms = 0; ms < 2; ++ms)
          sacc[st][ms] = __builtin_amdgcn_mfma_f32_16x16x32_bf16(kfU[ms][ch], qf[st][ch], sacc[st][ms], 0, 0, 0);
    __builtin_amdgcn_s_setprio(0);
    loadK(kfN, (i + 1 < 32) ? i + 1 : 31);  // K(i+1): full-iteration lead
    bf16x8 pf[2];
#pragma unroll
    for (int st = 0; st < 2; ++st) {
      float tm = -1e30f;
#pragma unroll
      for (int ms = 0; ms < 2; ++ms)
#pragma unroll
        for (int r = 0; r < 4; ++r) tm = fmaxf(tm, sacc[st][ms][r]);
      tm = fmaxf(tm, __shfl_xor(tm, 16));
      tm = fmaxf(tm, __shfl_xor(tm, 32));
      if (!__all(tm <= mrun[st] + 8.f)) {  // defer-max (base-2: P <= 2^8)
        float mnew = fmaxf(mrun[st], tm);
        float alpha = exp2f(mrun[st] - mnew);
        lrun[st] *= alpha;
#pragma unroll
        for (int cs = 0; cs < 8; ++cs) Of[st][cs] *= alpha;
        mrun[st] = mnew;
      }
      float ps = 0.f;
#pragma unroll
      for (int ms = 0; ms < 2; ++ms)
#pragma unroll
        for (int r = 0; r < 4; ++r) {
          float e = exp2f(sacc[st][ms][r] - mrun[st]);
          sacc[st][ms][r] = e;
          ps += e;
        }
      ps += __shfl_xor(ps, 16);
      ps += __shfl_xor(ps, 32);
      lrun[st] += ps;
#pragma unroll
      for (int j = 0; j < 8; ++j)
        pf[st][j] = (__bf16)sacc[st][j >> 2][j & 3];
    }
    __builtin_amdgcn_s_setprio(1);
#pragma unroll
    for (int cs = 0; cs < 8; ++cs)
#pragma unroll
      for (int st = 0; st < 2; ++st)
        Of[st][cs] = __builtin_amdgcn_mfma_f32_16x16x32_bf16(vf[cs], pf[st], Of[st][cs], 0, 0, 0);
    __builtin_amdgcn_s_setprio(0);
  };

  loadK(kfA, 0);
#pragma unroll 1
  for (int i = 0; i < 32; i += 2) {
    step(kfA, kfB, i);
    step(kfB, kfA, i + 1);
  }

  // 4-way merge: groups 1..3 write partials, group 0 combines.
  __syncthreads();
  if (grp) {
    float* rec = xch + (size_t)((grp - 1) * 128 + w2 * 64 + lane) * 69;
#pragma unroll
    for (int st = 0; st < 2; ++st) {
#pragma unroll
      for (int cs = 0; cs < 8; ++cs)
#pragma unroll
        for (int q = 0; q < 4; ++q) rec[st * 34 + cs * 4 + q] = Of[st][cs][q];
      rec[st * 34 + 32] = mrun[st];
      rec[st * 34 + 33] = lrun[st];
    }
  }
  __syncthreads();
  if (grp == 0) {
    float* outp = G2p + (size_t)b * CC * HWN;
#pragma unroll
    for (int st = 0; st < 2; ++st) {
      const float* r1 = xch + (size_t)(0 * 128 + w2 * 64 + lane) * 69 + st * 34;
      const float* r2 = xch + (size_t)(1 * 128 + w2 * 64 + lane) * 69 + st * 34;
      const float* r3 = xch + (size_t)(2 * 128 + w2 * 64 + lane) * 69 + st * 34;
      float m1 = r1[32], m2 = r2[32], m3 = r3[32];
      float mm = fmaxf(fmaxf(mrun[st], m1), fmaxf(m2, m3));
      float a0 = exp2f(mrun[st] - mm), a1 = exp2f(m1 - mm);
      float a2 = exp2f(m2 - mm), a3 = exp2f(m3 - mm);
      float inv = 1.f / (lrun[st] * a0 + r1[33] * a1 + r2[33] * a2 + r3[33] * a3);
      int n_l = ntile * 64 + w2 * 32 + st * 16 + l15;
#pragma unroll
      for (int cs = 0; cs < 8; ++cs)
#pragma unroll
        for (int q = 0; q < 4; ++q) {
          float v = Of[st][cs][q] * a0 + r1[cs * 4 + q] * a1 + r2[cs * 4 + q] * a2 + r3[cs * 4 + q] * a3;
          outp[(size_t)(cs * 16 + 4 * g + q) * HWN + n_l] = v * inv;
        }
    }
  }
}

// ---------------- per-(b,c) row softmax stats of G2_pre over n ------------------
__global__ __launch_bounds__(256) void smstats_kernel(
    const float* __restrict__ G2p, float2* __restrict__ smst) {
  int row = blockIdx.x;
  const float* x = G2p + (size_t)row * HWN;
  int tid = threadIdx.x;
  float v[16];
  float mx = -1e30f;
#pragma unroll
  for (int i = 0; i < 16; ++i) { v[i] = x[tid + i * 256]; mx = fmaxf(mx, v[i]); }
#pragma unroll
  for (int off = 32; off > 0; off >>= 1) mx = fmaxf(mx, __shfl_xor(mx, off));
  __shared__ float rm[4], rs[4];
  int wid = tid >> 6;
  if ((tid & 63) == 0) rm[wid] = mx;
  __syncthreads();
  float bmax = fmaxf(fmaxf(rm[0], rm[1]), fmaxf(rm[2], rm[3]));
  float s = 0.f;
#pragma unroll
  for (int i = 0; i < 16; ++i) s += __expf(v[i] - bmax);
#pragma unroll
  for (int off = 32; off > 0; off >>= 1) s += __shfl_xor(s, off);
  if ((tid & 63) == 0) rs[wid] = s;
  __syncthreads();
  if (tid == 0) {
    float tot = rs[0] + rs[1] + rs[2] + rs[3];
    smst[row] = make_float2(bmax, 1.f / tot);
  }
}

// ---------------- gamma/beta = channel-weighted sums of softmaxed G2 ------------
__global__ __launch_bounds__(256) void gammabeta_kernel(
    const float* __restrict__ G2p, const float2* __restrict__ smst,
    const float* __restrict__ gw, const float* __restrict__ bw,
    float* __restrict__ gamma, float* __restrict__ beta) {
  int b = blockIdx.y;
  int lane = threadIdx.x & 63;
  int cg = threadIdx.x >> 6;
  int m = blockIdx.x * 64 + lane;
  const float* base = G2p + (size_t)b * CC * HWN + m;
  float ag = 0.f, ab = 0.f;
#pragma unroll 8
  for (int ci = 0; ci < 32; ++ci) {
    int c = cg * 32 + ci;
    float2 st = smst[b * CC + c];
    float val = __expf(base[(size_t)c * HWN] - st.x) * st.y;
    ag = fmaf(gw[c], val, ag);
    ab = fmaf(bw[c], val, ab);
  }
  __shared__ float sg[4][64], sb[4][64];
  sg[cg][lane] = ag;
  sb[cg][lane] = ab;
  __syncthreads();
  if (threadIdx.x < 64) {
    int t = threadIdx.x;
    gamma[b * HWN + blockIdx.x * 64 + t] = sg[0][t] + sg[1][t] + sg[2][t] + sg[3][t];
    beta[b * HWN + blockIdx.x * 64 + t]  = sb[0][t] + sb[1][t] + sb[2][t] + sb[3][t];
  }
}

// ---- out[b,o] = T[b,o]@Gam[b] + rowsum(out_w[o,:])*Beta[b] + out_b[o] ----------
__global__ __launch_bounds__(256) void final_kernel(
    const float* __restrict__ Tf, const float* __restrict__ gamma,
    const float* __restrict__ beta, const float* __restrict__ outw,
    const float* __restrict__ outb, float* __restrict__ out) {
  int o = blockIdx.x, b = blockIdx.y;
  int j = threadIdx.x & 63;
  int wid = __builtin_amdgcn_readfirstlane(threadIdx.x >> 6);
  const float* gb_ = gamma + (size_t)b * HWN;
  float gr[64];
#pragma unroll
  for (int k = 0; k < 64; ++k) gr[k] = gb_[k * 64 + j];
  float wb = 0.f;
#pragma unroll 16
  for (int c = 0; c < CC; ++c) wb += outw[o * CC + c];
  float ob = outb[o];
  const float* trow0 = Tf + ((size_t)b * CC + o) * HWN;
  const float* bbase = beta + (size_t)b * HWN;
  float* obase = out + ((size_t)b * CC + o) * HWN;
#pragma unroll 4
  for (int r = 0; r < 16; ++r) {
    int i = r * 4 + wid;
    const float* tr = trow0 + i * 64;
    float a0 = 0.f, a1 = 0.f, a2 = 0.f, a3 = 0.f;
#pragma unroll
    for (int k = 0; k < 64; k += 4) {
      a0 = fmaf(tr[k],     gr[k],     a0);
      a1 = fmaf(tr[k + 1], gr[k + 1], a1);
      a2 = fmaf(tr[k + 2], gr[k + 2], a2);
      a3 = fmaf(tr[k + 3], gr[k + 3], a3);
    }
    obase[i * 64 + j] = (a0 + a1) + (a2 + a3) + wb * bbase[i * 64 + j] + ob;
  }
}

extern "C" void kernel_launch(void* const* d_in, const int* in_sizes, int n_in,
                              void* d_out, int out_size, void* d_ws, size_t ws_size,
                              hipStream_t stream) {
  (void)in_sizes; (void)n_in; (void)out_size; (void)ws_size;
  const float* content  = (const float*)d_in[0];
  const float* guidance = (const float*)d_in[1];
  const float* g1w = (const float*)d_in[2];
  const float* g1b = (const float*)d_in[3];
  const float* fw  = (const float*)d_in[4];
  const float* fb  = (const float*)d_in[5];
  const float* hwt = (const float*)d_in[6];
  const float* hb  = (const float*)d_in[7];
  const float* gw  = (const float*)d_in[8];
  const float* bw  = (const float*)d_in[9];
  const float* outw = (const float*)d_in[10];
  const float* outb = (const float*)d_in[11];

  char* ws = (char*)d_ws;
  const size_t MB_ = 1u << 20;
  float*  Tf  = (float*)(ws + 0);            // 8 MB
  float*  G2p = (float*)(ws + 8 * MB_);      // 8 MB
  __bf16* QTb = (__bf16*)(ws + 16 * MB_);    // 4 MB
  __bf16* KTb = (__bf16*)(ws + 20 * MB_);    // 4 MB
  __bf16* Vb  = (__bf16*)(ws + 24 * MB_);    // 4 MB
  float2* mom  = (float2*)(ws + 28 * MB_);                  // 8 KB
  float2* smst = (float2*)(ws + 28 * MB_ + 8192);           // 4 KB
  float*  gamma = (float*)(ws + 28 * MB_ + 16384);          // 64 KB
  float*  beta  = (float*)(ws + 28 * MB_ + 16384 + 65536);  // 64 KB
  float*  W2 = (float*)(ws + 28 * MB_ + 16384 + 2 * 65536); // 64 KB
  float*  b2 = (float*)(ws + 28 * MB_ + 16384 + 3 * 65536); // 512 B

  w2prep_kernel<<<dim3(CC), 128, 0, stream>>>(outw, g1w, g1b, W2, b2);
  moments_kernel<<<dim3(BB * CC, 2), 256, 0, stream>>>(content, guidance, mom);
  conv_kernel<<<dim3(HWN / 128, BB, 8), 256, 0, stream>>>(
      content, guidance, g1w, g1b, fw, fb, hwt, hb, W2, b2, mom,
      Tf, QTb, KTb, Vb);
  attn_kernel<<<dim3(256), 512, 0, stream>>>(QTb, KTb, Vb, G2p);
  smstats_kernel<<<dim3(BB * CC), 256, 0, stream>>>(G2p, smst);
  gammabeta_kernel<<<dim3(HWN / 64, BB), 256, 0, stream>>>(G2p, smst, gw, bw, gamma, beta);
  final_kernel<<<dim3(CC, BB), 256, 0, stream>>>(Tf, gamma, beta, outw, outb, (float*)d_out);
}

// Round 10
// 162.543 us; speedup vs baseline: 1.3812x; 1.3808x over previous
//
#include <hip/hip_runtime.h>
#include <stdint.h>
#include <stddef.h>

#define BB 4
#define CC 128
#define HWN 4096
#define LOG2E 1.4426950408889634f

typedef __bf16 bf16x2 __attribute__((ext_vector_type(2)));
typedef __bf16 bf16x8 __attribute__((ext_vector_type(8)));
typedef float f32x4 __attribute__((ext_vector_type(4)));
typedef float f32x16 __attribute__((ext_vector_type(16)));

__device__ __forceinline__ void g2l16(void* lds_ptr, const void* gptr) {
  __builtin_amdgcn_global_load_lds(
      (const __attribute__((address_space(1))) uint32_t*)gptr,
      (__attribute__((address_space(3))) uint32_t*)lds_ptr,
      16, 0, 0);
}

// k-slot permutation of mfma_32x32x16 within 16-elem groups:
// x = 4h + a + 8b (a 0..3, b 0..1, h = lane-half) -> 8h + 4b + a
__device__ __forceinline__ int p16(int x) {
  return ((x & 4) << 1) | ((x & 8) >> 1) | (x & 3);
}

// ---------------- W2 = out_w @ g1w, b2 = out_w @ g1b (f32, tiny) ----------------
__global__ __launch_bounds__(128) void w2prep_kernel(
    const float* __restrict__ outw, const float* __restrict__ g1w,
    const float* __restrict__ g1b, float* __restrict__ W2, float* __restrict__ b2) {
  int o = blockIdx.x;
  int c = threadIdx.x;
  float acc = 0.f;
#pragma unroll 8
  for (int k = 0; k < CC; ++k)
    acc = fmaf(outw[o * CC + k], g1w[k * CC + c], acc);
  W2[o * CC + c] = acc;
  if (c == 0) {
    float s = 0.f;
#pragma unroll 8
    for (int k = 0; k < CC; ++k) s = fmaf(outw[o * CC + k], g1b[k], s);
    b2[o] = s;
  }
}

// ---------------- per-(b,c) mean/rstd over HW (unbiased var, +eps) -------------
__global__ __launch_bounds__(256) void moments_kernel(
    const float* __restrict__ content, const float* __restrict__ guidance,
    float2* __restrict__ mom) {
  int row = blockIdx.x;  // b*C + c
  const float* x = (blockIdx.y ? guidance : content) + (size_t)row * HWN;
  int tid = threadIdx.x;
  float s1 = 0.f, s2 = 0.f;
#pragma unroll
  for (int i = 0; i < 16; ++i) {
    float v = x[tid + i * 256];
    s1 += v; s2 += v * v;
  }
#pragma unroll
  for (int off = 32; off > 0; off >>= 1) {
    s1 += __shfl_down(s1, off);
    s2 += __shfl_down(s2, off);
  }
  __shared__ float r1[4], r2[4];
  int wid = tid >> 6;
  if ((tid & 63) == 0) { r1[wid] = s1; r2[wid] = s2; }
  __syncthreads();
  if (tid == 0) {
    float t1 = r1[0] + r1[1] + r1[2] + r1[3];
    float t2 = r2[0] + r2[1] + r2[2] + r2[3];
    float mean = t1 * (1.f / HWN);
    float var = (t2 - (float)HWN * mean * mean) * (1.f / (HWN - 1));
    mom[blockIdx.y * (BB * CC) + row] = make_float2(mean, rsqrtf(var + 1e-5f));
  }
}

// ---------------- 1x1 conv: 4 modes, one launch, 2 p per thread -----------------
// mode 0: KT  = bf16(g1w@mvn(content)+g1b), transposed [p][p16 ch]
// mode 1: QT  = bf16((fw@mvn(guidance)+fb)*LOG2E), transposed [p][p16 ch]
// mode 2: V   = bf16(hw@guidance+hb), [c][p16 p]
// mode 3: T   = W2@mvn(content)+b2, f32 [c][p]  (G1 never materialized)
__global__ __launch_bounds__(256, 4) void conv_kernel(
    const float* __restrict__ content, const float* __restrict__ guidance,
    const float* __restrict__ g1w, const float* __restrict__ g1b,
    const float* __restrict__ fw, const float* __restrict__ fb,
    const float* __restrict__ hwt, const float* __restrict__ hb,
    const float* __restrict__ W2, const float* __restrict__ b2,
    const float2* __restrict__ mom,
    float* __restrict__ Tf,
    __bf16* __restrict__ QTb, __bf16* __restrict__ KTb, __bf16* __restrict__ Vb) {
  int zc = blockIdx.z;
  int mode = zc >> 1;
  int ohalf = zc & 1;
  int b = blockIdx.y;
  int lane = threadIdx.x & 63;
  int wid = threadIdx.x >> 6;
  int swid = __builtin_amdgcn_readfirstlane(wid);
  int p0 = blockIdx.x * 128 + lane * 2;
  const float* x; const float* w; const float* bias; const float2* mm;
  if (mode == 0)      { x = content;  w = g1w; bias = g1b; mm = mom; }
  else if (mode == 1) { x = guidance; w = fw;  bias = fb;  mm = mom + BB * CC; }
  else if (mode == 2) { x = guidance; w = hwt; bias = hb;  mm = nullptr; }
  else                { x = content;  w = W2;  bias = b2;  mm = mom; }
  const float* xb = x + (size_t)b * CC * HWN;
  const float2* mb = mm ? mm + b * CC : nullptr;
  int obase = ohalf * 64 + 2 * wid;
  const float* wbase = w + (size_t)(ohalf * 64 + 2 * swid) * CC;  // scalar base
  float2 acc[16];
#pragma unroll
  for (int k = 0; k < 8; ++k) {
    float b0 = bias[obase + 8 * k], b1 = bias[obase + 8 * k + 1];
    acc[2 * k] = make_float2(b0, b0);
    acc[2 * k + 1] = make_float2(b1, b1);
  }
#pragma unroll 2
  for (int c0 = 0; c0 < CC; c0 += 4) {
    float2 xv[4];
#pragma unroll
    for (int j = 0; j < 4; ++j) {
      float2 raw = *(const float2*)(xb + (size_t)(c0 + j) * HWN + p0);
      if (mb) {
        float2 ms = mb[c0 + j];
        raw.x = (raw.x - ms.x) * ms.y;
        raw.y = (raw.y - ms.x) * ms.y;
      }
      xv[j] = raw;
    }
#pragma unroll
    for (int k = 0; k < 8; ++k) {
      const float4 w0 = *(const float4*)(wbase + (size_t)(8 * k) * CC + c0);
      const float4 w1 = *(const float4*)(wbase + (size_t)(8 * k + 1) * CC + c0);
      acc[2 * k].x     = fmaf(w0.x, xv[0].x, fmaf(w0.y, xv[1].x, fmaf(w0.z, xv[2].x, fmaf(w0.w, xv[3].x, acc[2 * k].x))));
      acc[2 * k].y     = fmaf(w0.x, xv[0].y, fmaf(w0.y, xv[1].y, fmaf(w0.z, xv[2].y, fmaf(w0.w, xv[3].y, acc[2 * k].y))));
      acc[2 * k + 1].x = fmaf(w1.x, xv[0].x, fmaf(w1.y, xv[1].x, fmaf(w1.z, xv[2].x, fmaf(w1.w, xv[3].x, acc[2 * k + 1].x))));
      acc[2 * k + 1].y = fmaf(w1.x, xv[0].y, fmaf(w1.y, xv[1].y, fmaf(w1.z, xv[2].y, fmaf(w1.w, xv[3].y, acc[2 * k + 1].y))));
    }
  }
  if (mode <= 1) {
    __bf16* T = (mode == 0) ? KTb : QTb;
    float scale = (mode == 1) ? LOG2E : 1.f;
    char* row0 = (char*)(T + ((size_t)b * HWN + p0) * CC);
    char* row1 = row0 + CC * 2;
#pragma unroll
    for (int k = 0; k < 8; ++k) {
      int o0 = obase + 8 * k;
      int pp = (o0 & ~15) | p16(o0 & 15);  // o0 even -> pp, pp+1 adjacent
      bf16x2 pr0 = {(__bf16)(acc[2 * k].x * scale), (__bf16)(acc[2 * k + 1].x * scale)};
      bf16x2 pr1 = {(__bf16)(acc[2 * k].y * scale), (__bf16)(acc[2 * k + 1].y * scale)};
      *(bf16x2*)(row0 + pp * 2) = pr0;
      *(bf16x2*)(row1 + pp * 2) = pr1;
    }
  } else if (mode == 2) {
    int pstore = (p0 & ~15) | p16(p0 & 15);  // p0 even -> +1 adjacent
#pragma unroll
    for (int k = 0; k < 8; ++k) {
      int o0 = obase + 8 * k;
      bf16x2 v0 = {(__bf16)acc[2 * k].x, (__bf16)acc[2 * k].y};
      bf16x2 v1 = {(__bf16)acc[2 * k + 1].x, (__bf16)acc[2 * k + 1].y};
      *(bf16x2*)(Vb + ((size_t)b * CC + o0) * HWN + pstore) = v0;
      *(bf16x2*)(Vb + ((size_t)b * CC + o0 + 1) * HWN + pstore) = v1;
    }
  } else {
#pragma unroll
    for (int k = 0; k < 8; ++k) {
      int o0 = obase + 8 * k;
      *(float2*)(Tf + ((size_t)b * CC + o0) * HWN + p0) = acc[2 * k];
      *(float2*)(Tf + ((size_t)b * CC + o0 + 1) * HWN + p0) = acc[2 * k + 1];
    }
  }
}

// ---------------- flash attention: G2_pre[c,n] = sum_m V[c,m]*softmax_m(S[n,m]) --
// 32x32x16 MFMA: lane holds S[m-slice][ONE n] -> per-lane softmax, single
// shfl_xor(32) per reduce (no 16-lane shfl, no multi-strip). 8 waves =
// 4 m-groups x 2 n-waves; 32-m tiles; R4-proven LDS staging + syncthreads.
__global__ __launch_bounds__(512, 2) void attn_kernel(
    const __bf16* __restrict__ QTb, const __bf16* __restrict__ KTb,
    const __bf16* __restrict__ Vb, float* __restrict__ G2p) {
  __shared__ __align__(16) char lds[131072];  // 8 slots x (K 8KB + V 8KB)
  int fid = blockIdx.x;
  int swz = (fid & 7) * 32 + (fid >> 3);  // XCD swizzle
  int b = swz >> 6;
  int ntile = swz & 63;
  int tid = threadIdx.x;
  int lane = tid & 63;
  int wid = tid >> 6;   // 0..7
  int grp = wid >> 1;   // m-group: tiles t % 4 == grp
  int w2 = wid & 1;     // n-wave
  int l31 = lane & 31;
  int h = lane >> 5;
  int nb = ntile * 64 + w2 * 32;

  // Q fragments: lane (n=l31, half h) holds 8 ch per 16-ch group (p16 order)
  bf16x8 qf[8];
  {
    const char* qrow = (const char*)(QTb + ((size_t)b * HWN + nb + l31) * CC);
#pragma unroll
    for (int i = 0; i < 8; ++i)
      qf[i] = *(const bf16x8*)(qrow + i * 32 + h * 16);
  }

  f32x16 Of[4];  // c-tiles 0..3: O[c = 32q + (r&3)+8(r>>2)+4h][n = nb+l31]
#pragma unroll
  for (int q = 0; q < 4; ++q)
#pragma unroll
    for (int r = 0; r < 16; ++r) Of[q][r] = 0.f;
  float mrun = -1e30f, lrun = 0.f;

  const char* ktB = (const char*)(KTb + (size_t)b * HWN * CC);  // [m][p16 ch] 256B rows
  const char* vB  = (const char*)(Vb + (size_t)b * CC * HWN);   // [c][p16 m] 8192B rows

  // stage tile t=4q+grp into slot t&7: w2=0 stages K (8KB), w2=1 V (8KB).
  // LDS dest linear; global source pre-swizzled (K: chunk^row&15, V: u^(c>>1)&3)
  auto stage = [&](int q) {
    int t = q * 4 + grp;
    int m0 = t * 32;
    char* buf = lds + (size_t)(t & 7) * 16384;
    if (w2 == 0) {  // K tile [32 m][256B]
#pragma unroll
      for (int i = 0; i < 8; ++i) {
        int row = i * 4 + (lane >> 4);
        int chk = (lane & 15) ^ (row & 15);
        g2l16(buf + i * 1024, ktB + (size_t)(m0 + row) * 256 + chk * 16);
      }
    } else {  // V tile [128 c][64B]
#pragma unroll
      for (int i = 0; i < 8; ++i) {
        int c = i * 16 + (lane >> 2);
        int ug = (lane & 3) ^ ((c >> 1) & 3);
        g2l16(buf + 8192 + i * 1024, vB + (size_t)c * (HWN * 2) + (size_t)m0 * 2 + ug * 16);
      }
    }
  };

  auto compute = [&](int t) {
    const char* kt = lds + (size_t)(t & 7) * 16384;
    const char* vv = kt + 8192;
    bf16x8 kf[8];
#pragma unroll
    for (int i = 0; i < 8; ++i) {
      int chk = (2 * i + h) ^ (l31 & 15);
      kf[i] = *(const bf16x8*)(kt + l31 * 256 + chk * 16);
    }
    f32x16 sa, sb;
#pragma unroll
    for (int r = 0; r < 16; ++r) { sa[r] = 0.f; sb[r] = 0.f; }
#pragma unroll
    for (int i = 0; i < 8; i += 2) {  // 2 independent accum chains
      sa = __builtin_amdgcn_mfma_f32_32x32x16_bf16(kf[i],     qf[i],     sa, 0, 0, 0);
      sb = __builtin_amdgcn_mfma_f32_32x32x16_bf16(kf[i + 1], qf[i + 1], sb, 0, 0, 0);
    }
    bf16x8 vf[8];  // issued here, consumed after softmax (latency hidden)
#pragma unroll
    for (int cs = 0; cs < 4; ++cs) {
      int cr = cs * 32 + l31;
      int d = (cr >> 1) & 3;
#pragma unroll
      for (int kk = 0; kk < 2; ++kk)
        vf[cs * 2 + kk] = *(const bf16x8*)(vv + cr * 64 + (((2 * kk + h) ^ d) << 4));
    }
    f32x16 s = sa + sb;
    // lane-local softmax: lane holds 16 of 32 m for its n; partner lane^32 rest
    float tm = s[0];
#pragma unroll
    for (int r = 1; r < 16; ++r) tm = fmaxf(tm, s[r]);
    tm = fmaxf(tm, __shfl_xor(tm, 32));
    if (!__all(tm <= mrun + 8.f)) {  // defer-max (base-2: P <= 2^8)
      float mnew = fmaxf(mrun, tm);
      float alpha = exp2f(mrun - mnew);
      lrun *= alpha;
#pragma unroll
      for (int q = 0; q < 4; ++q) Of[q] *= alpha;
      mrun = mnew;
    }
    float pe[16];
    float ps = 0.f;
#pragma unroll
    for (int r = 0; r < 16; ++r) { pe[r] = exp2f(s[r] - mrun); ps += pe[r]; }
    ps += __shfl_xor(ps, 32);
    lrun += ps;
    // S-reg -> PV B-operand k-slot mapping is identity: pure per-lane cvt
    bf16x8 pf0, pf1;
#pragma unroll
    for (int j = 0; j < 8; ++j) { pf0[j] = (__bf16)pe[j]; pf1[j] = (__bf16)pe[8 + j]; }
#pragma unroll
    for (int cs = 0; cs < 4; ++cs) {
      Of[cs] = __builtin_amdgcn_mfma_f32_32x32x16_bf16(vf[cs * 2],     pf0, Of[cs], 0, 0, 0);
      Of[cs] = __builtin_amdgcn_mfma_f32_32x32x16_bf16(vf[cs * 2 + 1], pf1, Of[cs], 0, 0, 0);
    }
  };

  stage(0);
  __syncthreads();
  for (int pt = 0; pt < 32; ++pt) {
    if (pt < 31) stage(pt + 1);  // prefetch into other slot, full-compute lead
    compute(4 * pt + grp);
    __syncthreads();
  }

  // 4-way m-merge: groups 1..3 write partials, group 0 combines + writes G2p
  float* xch = (float*)lds;
  if (grp) {
    float* rec = xch + (size_t)((grp - 1) * 128 + w2 * 64 + lane) * 68;
#pragma unroll
    for (int q = 0; q < 4; ++q)
#pragma unroll
      for (int r = 0; r < 16; ++r) rec[q * 16 + r] = Of[q][r];
    rec[64] = mrun;
    rec[65] = lrun;
  }
  __syncthreads();
  if (grp == 0) {
    const float* r1 = xch + (size_t)(0 * 128 + w2 * 64 + lane) * 68;
    const float* r2 = xch + (size_t)(1 * 128 + w2 * 64 + lane) * 68;
    const float* r3 = xch + (size_t)(2 * 128 + w2 * 64 + lane) * 68;
    float m1 = r1[64], m2 = r2[64], m3 = r3[64];
    float mm = fmaxf(fmaxf(mrun, m1), fmaxf(m2, m3));
    float a0 = exp2f(mrun - mm), a1 = exp2f(m1 - mm);
    float a2 = exp2f(m2 - mm), a3 = exp2f(m3 - mm);
    float inv = 1.f / (lrun * a0 + r1[65] * a1 + r2[65] * a2 + r3[65] * a3);
    float* outp = G2p + (size_t)b * CC * HWN + nb + l31;
#pragma unroll
    for (int q = 0; q < 4; ++q)
#pragma unroll
      for (int r = 0; r < 16; ++r) {
        int c = q * 32 + (r & 3) + 8 * (r >> 2) + 4 * h;
        float v = Of[q][r] * a0 + r1[q * 16 + r] * a1 + r2[q * 16 + r] * a2 + r3[q * 16 + r] * a3;
        outp[(size_t)c * HWN] = v * inv;
      }
  }
}

// ---------------- per-(b,c) row softmax stats of G2_pre over n ------------------
__global__ __launch_bounds__(256) void smstats_kernel(
    const float* __restrict__ G2p, float2* __restrict__ smst) {
  int row = blockIdx.x;
  const float* x = G2p + (size_t)row * HWN;
  int tid = threadIdx.x;
  float v[16];
  float mx = -1e30f;
#pragma unroll
  for (int i = 0; i < 16; ++i) { v[i] = x[tid + i * 256]; mx = fmaxf(mx, v[i]); }
#pragma unroll
  for (int off = 32; off > 0; off >>= 1) mx = fmaxf(mx, __shfl_xor(mx, off));
  __shared__ float rm[4], rs[4];
  int wid = tid >> 6;
  if ((tid & 63) == 0) rm[wid] = mx;
  __syncthreads();
  float bmax = fmaxf(fmaxf(rm[0], rm[1]), fmaxf(rm[2], rm[3]));
  float s = 0.f;
#pragma unroll
  for (int i = 0; i < 16; ++i) s += __expf(v[i] - bmax);
#pragma unroll
  for (int off = 32; off > 0; off >>= 1) s += __shfl_xor(s, off);
  if ((tid & 63) == 0) rs[wid] = s;
  __syncthreads();
  if (tid == 0) {
    float tot = rs[0] + rs[1] + rs[2] + rs[3];
    smst[row] = make_float2(bmax, 1.f / tot);
  }
}

// ---------------- gamma/beta = channel-weighted sums of softmaxed G2 ------------
__global__ __launch_bounds__(256) void gammabeta_kernel(
    const float* __restrict__ G2p, const float2* __restrict__ smst,
    const float* __restrict__ gw, const float* __restrict__ bw,
    float* __restrict__ gamma, float* __restrict__ beta) {
  int b = blockIdx.y;
  int lane = threadIdx.x & 63;
  int cg = threadIdx.x >> 6;
  int m = blockIdx.x * 64 + lane;
  const float* base = G2p + (size_t)b * CC * HWN + m;
  float ag = 0.f, ab = 0.f;
#pragma unroll 8
  for (int ci = 0; ci < 32; ++ci) {
    int c = cg * 32 + ci;
    float2 st = smst[b * CC + c];
    float val = __expf(base[(size_t)c * HWN] - st.x) * st.y;
    ag = fmaf(gw[c], val, ag);
    ab = fmaf(bw[c], val, ab);
  }
  __shared__ float sg[4][64], sb[4][64];
  sg[cg][lane] = ag;
  sb[cg][lane] = ab;
  __syncthreads();
  if (threadIdx.x < 64) {
    int t = threadIdx.x;
    gamma[b * HWN + blockIdx.x * 64 + t] = sg[0][t] + sg[1][t] + sg[2][t] + sg[3][t];
    beta[b * HWN + blockIdx.x * 64 + t]  = sb[0][t] + sb[1][t] + sb[2][t] + sb[3][t];
  }
}

// ---- out[b,o] = T[b,o]@Gam[b] + rowsum(out_w[o,:])*Beta[b] + out_b[o] ----------
__global__ __launch_bounds__(256) void final_kernel(
    const float* __restrict__ Tf, const float* __restrict__ gamma,
    const float* __restrict__ beta, const float* __restrict__ outw,
    const float* __restrict__ outb, float* __restrict__ out) {
  int o = blockIdx.x, b = blockIdx.y;
  int j = threadIdx.x & 63;
  int wid = __builtin_amdgcn_readfirstlane(threadIdx.x >> 6);
  const float* gb_ = gamma + (size_t)b * HWN;
  float gr[64];
#pragma unroll
  for (int k = 0; k < 64; ++k) gr[k] = gb_[k * 64 + j];
  float wb = 0.f;
#pragma unroll 16
  for (int c = 0; c < CC; ++c) wb += outw[o * CC + c];
  float ob = outb[o];
  const float* trow0 = Tf + ((size_t)b * CC + o) * HWN;
  const float* bbase = beta + (size_t)b * HWN;
  float* obase = out + ((size_t)b * CC + o) * HWN;
#pragma unroll 4
  for (int r = 0; r < 16; ++r) {
    int i = r * 4 + wid;
    const float* tr = trow0 + i * 64;
    float a0 = 0.f, a1 = 0.f, a2 = 0.f, a3 = 0.f;
#pragma unroll
    for (int k = 0; k < 64; k += 4) {
      a0 = fmaf(tr[k],     gr[k],     a0);
      a1 = fmaf(tr[k + 1], gr[k + 1], a1);
      a2 = fmaf(tr[k + 2], gr[k + 2], a2);
      a3 = fmaf(tr[k + 3], gr[k + 3], a3);
    }
    obase[i * 64 + j] = (a0 + a1) + (a2 + a3) + wb * bbase[i * 64 + j] + ob;
  }
}

extern "C" void kernel_launch(void* const* d_in, const int* in_sizes, int n_in,
                              void* d_out, int out_size, void* d_ws, size_t ws_size,
                              hipStream_t stream) {
  (void)in_sizes; (void)n_in; (void)out_size; (void)ws_size;
  const float* content  = (const float*)d_in[0];
  const float* guidance = (const float*)d_in[1];
  const float* g1w = (const float*)d_in[2];
  const float* g1b = (const float*)d_in[3];
  const float* fw  = (const float*)d_in[4];
  const float* fb  = (const float*)d_in[5];
  const float* hwt = (const float*)d_in[6];
  const float* hb  = (const float*)d_in[7];
  const float* gw  = (const float*)d_in[8];
  const float* bw  = (const float*)d_in[9];
  const float* outw = (const float*)d_in[10];
  const float* outb = (const float*)d_in[11];

  char* ws = (char*)d_ws;
  const size_t MB_ = 1u << 20;
  float*  Tf  = (float*)(ws + 0);            // 8 MB
  float*  G2p = (float*)(ws + 8 * MB_);      // 8 MB
  __bf16* QTb = (__bf16*)(ws + 16 * MB_);    // 4 MB
  __bf16* KTb = (__bf16*)(ws + 20 * MB_);    // 4 MB
  __bf16* Vb  = (__bf16*)(ws + 24 * MB_);    // 4 MB
  float2* mom  = (float2*)(ws + 28 * MB_);                  // 8 KB
  float2* smst = (float2*)(ws + 28 * MB_ + 8192);           // 4 KB
  float*  gamma = (float*)(ws + 28 * MB_ + 16384);          // 64 KB
  float*  beta  = (float*)(ws + 28 * MB_ + 16384 + 65536);  // 64 KB
  float*  W2 = (float*)(ws + 28 * MB_ + 16384 + 2 * 65536); // 64 KB
  float*  b2 = (float*)(ws + 28 * MB_ + 16384 + 3 * 65536); // 512 B

  w2prep_kernel<<<dim3(CC), 128, 0, stream>>>(outw, g1w, g1b, W2, b2);
  moments_kernel<<<dim3(BB * CC, 2), 256, 0, stream>>>(content, guidance, mom);
  conv_kernel<<<dim3(HWN / 128, BB, 8), 256, 0, stream>>>(
      content, guidance, g1w, g1b, fw, fb, hwt, hb, W2, b2, mom,
      Tf, QTb, KTb, Vb);
  attn_kernel<<<dim3(256), 512, 0, stream>>>(QTb, KTb, Vb, G2p);
  smstats_kernel<<<dim3(BB * CC), 256, 0, stream>>>(G2p, smst);
  gammabeta_kernel<<<dim3(HWN / 64, BB), 256, 0, stream>>>(G2p, smst, gw, bw, gamma, beta);
  final_kernel<<<dim3(CC, BB), 256, 0, stream>>>(Tf, gamma, beta, outw, outb, (float*)d_out);
}